// Round 6
// baseline (1984.099 us; speedup 1.0000x reference)
//
#include <hip/hip_runtime.h>
#include <hip/hip_bf16.h>
#include <stdint.h>

#define B_SZ   8
#define N_PTS  131072
#define L_TOK  8191
#define M_TOK  (B_SZ * L_TOK)   // 65528

typedef unsigned long long u64;
typedef unsigned int u32;
typedef __hip_bfloat16 bf16;

// ---------- monotonic float<->uint mapping for atomic min/max ----------
__device__ __forceinline__ u32 f2u_mono(float f) {
  u32 u = __float_as_uint(f);
  return (u & 0x80000000u) ? ~u : (u | 0x80000000u);
}
__device__ __forceinline__ float u2f_mono(u32 u) {
  u32 b = (u & 0x80000000u) ? (u ^ 0x80000000u) : ~u;
  return __uint_as_float(b);
}

__global__ void init_mm_kernel(u32* mm) {
  int t = threadIdx.x;
  if (t < 48) mm[t] = ((t % 6) < 3) ? 0xFFFFFFFFu : 0u;  // min-identity / max-identity
}

// ---------- per-batch per-coord min/max ----------
__global__ __launch_bounds__(256) void minmax_kernel(const float* __restrict__ pts,
                                                     u32* __restrict__ mm) {
  int b = blockIdx.x >> 6;          // 64 blocks per batch
  int chunk = blockIdx.x & 63;
  int base = b * N_PTS + chunk * 2048;
  float mn0 = 3.4e38f, mn1 = 3.4e38f, mn2 = 3.4e38f;
  float mx0 = -3.4e38f, mx1 = -3.4e38f, mx2 = -3.4e38f;
  for (int i = threadIdx.x; i < 2048; i += 256) {
    const float* p = pts + (size_t)(base + i) * 3;
    float x = p[0], y = p[1], z = p[2];
    mn0 = fminf(mn0, x); mx0 = fmaxf(mx0, x);
    mn1 = fminf(mn1, y); mx1 = fmaxf(mx1, y);
    mn2 = fminf(mn2, z); mx2 = fmaxf(mx2, z);
  }
  __shared__ u32 smn[3], smx[3];
  if (threadIdx.x < 3) { smn[threadIdx.x] = 0xFFFFFFFFu; smx[threadIdx.x] = 0u; }
  __syncthreads();
  atomicMin(&smn[0], f2u_mono(mn0)); atomicMin(&smn[1], f2u_mono(mn1)); atomicMin(&smn[2], f2u_mono(mn2));
  atomicMax(&smx[0], f2u_mono(mx0)); atomicMax(&smx[1], f2u_mono(mx1)); atomicMax(&smx[2], f2u_mono(mx2));
  __syncthreads();
  if (threadIdx.x < 3)       atomicMin(&mm[b * 6 + threadIdx.x], smn[threadIdx.x]);
  else if (threadIdx.x < 6)  atomicMax(&mm[b * 6 + threadIdx.x], smx[threadIdx.x - 3]);
}

// ---------- morton ----------
__device__ __forceinline__ u64 expand_bits(u64 v) {
  v = (v | (v << 32)) & 0x001F00000000FFFFull;
  v = (v | (v << 16)) & 0x001F0000FF0000FFull;
  v = (v | (v << 8))  & 0x100F00F00F00F00Full;
  v = (v | (v << 4))  & 0x10C30C30C30C30C3ull;
  v = (v | (v << 2))  & 0x1249249249249249ull;
  return v;
}

// Variant A: reciprocal-multiply quantization (XLA/LLVM -freciprocal-math
// lowering of (p-mn)/scale): rcp = CR f32 (1.0f/scale); two CR f32 muls.
// Harness compile is IEEE (proven R0==R2), so plain ops are correctly
// rounded; barriers still pin evaluation order/no-narrowing.
__device__ __forceinline__ long long quant1(float p, float mn, float mx) {
  float scale = fmaxf(mx - mn, 1e-8f);   // f32
  float num = p - mn;                    // f32 subtract
  float rcp = 1.0f / scale;              // CR f32 reciprocal
  asm volatile("" : "+v"(rcp));
  float normed = num * rcp;              // CR f32 multiply
  asm volatile("" : "+v"(normed));
  float scaled = normed * 1023.0f;       // CR f32 multiply
  asm volatile("" : "+v"(scaled));
  long long q = (long long)scaled;       // truncation toward zero
  q = q < 0 ? 0 : q; q = q > 1023 ? 1023 : q;
  return q;
}

__global__ __launch_bounds__(256) void morton_kernel(const float* __restrict__ pts,
                                                     const u32* __restrict__ mm,
                                                     u64* __restrict__ keys) {
  int gid = blockIdx.x * 256 + threadIdx.x;     // 0 .. B*N-1
  int b = gid >> 17;
  int i = gid & (N_PTS - 1);
  const u32* mb = mm + b * 6;
  float mn0 = u2f_mono(mb[0]), mn1 = u2f_mono(mb[1]), mn2 = u2f_mono(mb[2]);
  float mx0 = u2f_mono(mb[3]), mx1 = u2f_mono(mb[4]), mx2 = u2f_mono(mb[5]);
  const float* p = pts + (size_t)gid * 3;
  long long q0 = quant1(p[0], mn0, mx0);
  long long q1 = quant1(p[1], mn1, mx1);
  long long q2 = quant1(p[2], mn2, mx2);
  u64 m = expand_bits((u64)q0) * 4ull + expand_bits((u64)q1) * 2ull + expand_bits((u64)q2);
  keys[gid] = (m << 17) | (u64)i;   // morton in bits 17..46, idx in 0..16
}

// ---------- segmented stable LSD radix sort over morton bits (17..48) ----------
__global__ __launch_bounds__(256) void radix_hist(const u64* __restrict__ keys,
                                                  u32* __restrict__ hist, int shift) {
  int blk = blockIdx.x;            // 0..2047
  int b = blk >> 8, c = blk & 255;
  int t = threadIdx.x;
  __shared__ u32 h[256];
  h[t] = 0;
  __syncthreads();
  size_t base = ((size_t)b << 17) + (size_t)c * 512;
  u32 d0 = (u32)((keys[base + t] >> shift) & 255ull);
  u32 d1 = (u32)((keys[base + 256 + t] >> shift) & 255ull);
  atomicAdd(&h[d0], 1u);
  atomicAdd(&h[d1], 1u);
  __syncthreads();
  hist[((blk) << 8) + t] = h[t];   // hist[b][c][digit]
}

__global__ __launch_bounds__(256) void radix_scan(u32* __restrict__ hist) {
  int b = blockIdx.x;              // 0..7
  int d = threadIdx.x;             // digit
  u32 run = 0;
  for (int c = 0; c < 256; ++c) {
    int idx = ((b * 256 + c) << 8) + d;
    u32 v = hist[idx];
    hist[idx] = run;
    run += v;
  }
  __shared__ u32 s[256];
  s[d] = run;
  __syncthreads();
  for (int off = 1; off < 256; off <<= 1) {
    u32 v = (d >= off) ? s[d - off] : 0u;
    __syncthreads();
    s[d] += v;
    __syncthreads();
  }
  u32 digit_base = s[d] - run;
  for (int c = 0; c < 256; ++c) {
    int idx = ((b * 256 + c) << 8) + d;
    hist[idx] += digit_base;
  }
}

__global__ __launch_bounds__(512) void radix_scatter(const u64* __restrict__ keys_in,
                                                     u64* __restrict__ keys_out,
                                                     const u32* __restrict__ hist, int shift) {
  int blk = blockIdx.x;            // 0..2047
  int b = blk >> 8, c = blk & 255;
  int t = threadIdx.x;             // 0..511
  __shared__ u32 cnt[256];
  __shared__ u32 basebuf[256];
  if (t < 256) cnt[t] = hist[(blk << 8) + t];
  __syncthreads();
  size_t base = ((size_t)b << 17) + (size_t)c * 512;
  u64 key = keys_in[base + t];
  u32 d = (u32)((key >> shift) & 255ull);
  int wave = t >> 6, lane = t & 63;
  u32 dst = 0;
  for (int w = 0; w < 8; ++w) {
    if (wave == w) {
      u64 m = ~0ull;
      #pragma unroll
      for (int k = 0; k < 8; ++k) {
        u64 bb = __ballot((d >> k) & 1u);
        m &= ((d >> k) & 1u) ? bb : ~bb;
      }
      u64 lt = (1ull << lane) - 1ull;
      u32 rank = (u32)__popcll(m & lt);
      if (rank == 0)
        basebuf[d] = atomicAdd(&cnt[d], (u32)__popcll(m));
      dst = rank;
    }
    __syncthreads();
    if (wave == w) dst += basebuf[d];
    __syncthreads();
  }
  keys_out[((size_t)b << 17) + dst] = key;
}

// ---------- extract sort_idx + gather sorted points ----------
__global__ __launch_bounds__(256) void extract_kernel(const u64* __restrict__ keys,
                                                      const float* __restrict__ pts,
                                                      float* __restrict__ sp,
                                                      float* __restrict__ sidx) {
  int gid = blockIdx.x * 256 + threadIdx.x;
  u64 key = keys[gid];
  int idx = (int)(key & 0x1FFFFull);
  sidx[gid] = (float)idx;
  int b = gid >> 17;
  const float* src = pts + ((size_t)(b << 17) + idx) * 3;
  float* dst = sp + (size_t)gid * 3;
  dst[0] = src[0]; dst[1] = src[1]; dst[2] = src[2];
}

// ---------- patch MLP: centroid, (3->64->128)+relu+maxpool, pos MLP ----------
__global__ __launch_bounds__(128) void patch_kernel(
    const float* __restrict__ sp,
    const float* __restrict__ W1, const float* __restrict__ b1,
    const float* __restrict__ W2, const float* __restrict__ b2,
    const float* __restrict__ Wp1, const float* __restrict__ bp1,
    const float* __restrict__ Wp2, const float* __restrict__ bp2,
    bf16* __restrict__ comb, float* __restrict__ cent_out) {
  __shared__ __align__(16) float W2s[64 * 128];   // 32 KB
  __shared__ __align__(16) float hs[32 * 64];     // 8 KB
  __shared__ float ptsS[32 * 3];
  __shared__ float cen[3];
  __shared__ float hp[64];

  int blk = blockIdx.x;
  int b = blk / L_TOK;
  int l = blk - b * L_TOK;
  int t = threadIdx.x;
  size_t base = ((size_t)b * N_PTS + (size_t)l * 16) * 3;

  if (t < 96) ptsS[t] = sp[base + t];
  {
    const float4* src = (const float4*)W2;
    float4* dst = (float4*)W2s;
    #pragma unroll
    for (int i = t; i < 2048; i += 128) dst[i] = src[i];
  }
  __syncthreads();

  if (t < 3) {
    float s = 0.f;
    for (int p = 0; p < 32; ++p) s += ptsS[p * 3 + t];
    cen[t] = s * (1.0f / 32.0f);
  }
  __syncthreads();

  float c0 = cen[0], c1 = cen[1], c2 = cen[2];

  {
    int d = t & 63, half = t >> 6;
    float w1x = W1[d], w1y = W1[64 + d], w1z = W1[128 + d], b1d = b1[d];
    #pragma unroll
    for (int pp = 0; pp < 16; ++pp) {
      int p = pp * 2 + half;
      float x = ptsS[p * 3 + 0] - c0;
      float y = ptsS[p * 3 + 1] - c1;
      float z = ptsS[p * 3 + 2] - c2;
      float a = fmaf(x, w1x, fmaf(y, w1y, fmaf(z, w1z, b1d)));
      hs[p * 64 + d] = fmaxf(a, 0.0f);
    }
  }
  if (t < 64) {
    float a = fmaf(c0, Wp1[t], fmaf(c1, Wp1[64 + t], fmaf(c2, Wp1[128 + t], bp1[t])));
    hp[t] = fmaxf(a, 0.0f);
  }
  __syncthreads();

  float b2t = b2[t];
  float fmaxv = 0.0f;
  for (int p = 0; p < 32; ++p) {
    const float4* h4 = (const float4*)(hs + p * 64);
    float acc = b2t;
    #pragma unroll
    for (int q = 0; q < 16; ++q) {
      float4 hv = h4[q];
      int d0 = q * 4;
      acc = fmaf(hv.x, W2s[(d0 + 0) * 128 + t], acc);
      acc = fmaf(hv.y, W2s[(d0 + 1) * 128 + t], acc);
      acc = fmaf(hv.z, W2s[(d0 + 2) * 128 + t], acc);
      acc = fmaf(hv.w, W2s[(d0 + 3) * 128 + t], acc);
    }
    fmaxv = fmaxf(fmaxv, fmaxf(acc, 0.0f));
  }

  float pacc = bp2[t];
  #pragma unroll
  for (int d0 = 0; d0 < 64; d0 += 4) {
    float4 hv = *(const float4*)(hp + d0);
    pacc = fmaf(hv.x, Wp2[(d0 + 0) * 128 + t], pacc);
    pacc = fmaf(hv.y, Wp2[(d0 + 1) * 128 + t], pacc);
    pacc = fmaf(hv.z, Wp2[(d0 + 2) * 128 + t], pacc);
    pacc = fmaf(hv.w, Wp2[(d0 + 3) * 128 + t], pacc);
  }

  bf16* cb = comb + (size_t)blk * 256;
  cb[t] = __float2bfloat16(fmaxv);
  cb[128 + t] = __float2bfloat16(pacc);
  if (t < 3) cent_out[(size_t)blk * 3 + t] = cen[t];
}

// ---------- token projection GEMM: [M,256] @ [256,256] + bias ----------
__global__ __launch_bounds__(256) void proj_gemm(const bf16* __restrict__ A,
                                                 const float* __restrict__ W,
                                                 const float* __restrict__ bias,
                                                 float* __restrict__ C) {
  __shared__ float As[32][65];
  __shared__ float Bs[32][64];
  int t = threadIdx.x;
  int row0 = blockIdx.x * 64, col0 = blockIdx.y * 64;
  int tm = (t >> 4) << 2;
  int tn = (t & 15) << 2;
  float acc[4][4] = {{0.f}};
  for (int kc = 0; kc < 256; kc += 32) {
    #pragma unroll
    for (int e = 0; e < 8; ++e) {
      int idx = t + e * 256;
      int r = idx >> 5, kk = idx & 31;
      int row = row0 + r;
      As[kk][r] = (row < M_TOK) ? __bfloat162float(A[(size_t)row * 256 + kc + kk]) : 0.f;
      int kb = idx >> 6, n = idx & 63;
      Bs[kb][n] = W[(size_t)(kc + kb) * 256 + col0 + n];
    }
    __syncthreads();
    #pragma unroll
    for (int kk = 0; kk < 32; ++kk) {
      float a0 = As[kk][tm], a1 = As[kk][tm + 1], a2 = As[kk][tm + 2], a3 = As[kk][tm + 3];
      float b0 = Bs[kk][tn], b1v = Bs[kk][tn + 1], b2v = Bs[kk][tn + 2], b3v = Bs[kk][tn + 3];
      acc[0][0] = fmaf(a0, b0, acc[0][0]); acc[0][1] = fmaf(a0, b1v, acc[0][1]);
      acc[0][2] = fmaf(a0, b2v, acc[0][2]); acc[0][3] = fmaf(a0, b3v, acc[0][3]);
      acc[1][0] = fmaf(a1, b0, acc[1][0]); acc[1][1] = fmaf(a1, b1v, acc[1][1]);
      acc[1][2] = fmaf(a1, b2v, acc[1][2]); acc[1][3] = fmaf(a1, b3v, acc[1][3]);
      acc[2][0] = fmaf(a2, b0, acc[2][0]); acc[2][1] = fmaf(a2, b1v, acc[2][1]);
      acc[2][2] = fmaf(a2, b2v, acc[2][2]); acc[2][3] = fmaf(a2, b3v, acc[2][3]);
      acc[3][0] = fmaf(a3, b0, acc[3][0]); acc[3][1] = fmaf(a3, b1v, acc[3][1]);
      acc[3][2] = fmaf(a3, b2v, acc[3][2]); acc[3][3] = fmaf(a3, b3v, acc[3][3]);
    }
    __syncthreads();
  }
  float bx = bias[col0 + tn], by = bias[col0 + tn + 1], bz = bias[col0 + tn + 2], bw = bias[col0 + tn + 3];
  #pragma unroll
  for (int i2 = 0; i2 < 4; ++i2) {
    int row = row0 + tm + i2;
    if (row < M_TOK) {
      float4 o;
      o.x = acc[i2][0] + bx; o.y = acc[i2][1] + by;
      o.z = acc[i2][2] + bz; o.w = acc[i2][3] + bw;
      *(float4*)&C[(size_t)row * 256 + col0 + tn] = o;
    }
  }
}

extern "C" void kernel_launch(void* const* d_in, const int* in_sizes, int n_in,
                              void* d_out, int out_size, void* d_ws, size_t ws_size,
                              hipStream_t stream) {
  const float* points = (const float*)d_in[0];
  const float* W1 = (const float*)d_in[1];
  const float* b1 = (const float*)d_in[2];
  const float* W2 = (const float*)d_in[3];
  const float* b2 = (const float*)d_in[4];
  const float* Wp1 = (const float*)d_in[5];
  const float* bp1 = (const float*)d_in[6];
  const float* Wp2 = (const float*)d_in[7];
  const float* bp2 = (const float*)d_in[8];
  const float* Wproj = (const float*)d_in[9];
  const float* bproj = (const float*)d_in[10];

  float* out = (float*)d_out;
  float* tokens = out;                        // [8][8191][256]
  float* cents  = out + 16775168;             // [8][8191][3]
  float* sidx   = out + 16971752;             // [8][131072] as float

  char* ws = (char*)d_ws;
  u32* mm     = (u32*)ws;                                  // 192 B (pad to 256)
  u64* keysA  = (u64*)(ws + 256);                          // 8 MB
  float* sp   = (float*)(ws + 256 + 8388608);              // 12 MB
  char* combB = ws + 256 + 8388608 + 12582912;             // 32 MB region
  bf16* comb  = (bf16*)combB;
  u64* keysB  = (u64*)combB;                               // 8 MB (dead until extract)
  u32* hist   = (u32*)(combB + 8388608);                   // 2 MB

  init_mm_kernel<<<1, 64, 0, stream>>>(mm);
  minmax_kernel<<<512, 256, 0, stream>>>(points, mm);
  morton_kernel<<<4096, 256, 0, stream>>>(points, mm, keysA);

  const int shifts[4] = {17, 25, 33, 41};
  u64* src = keysA; u64* dst = keysB;
  for (int p = 0; p < 4; ++p) {
    radix_hist<<<2048, 256, 0, stream>>>(src, hist, shifts[p]);
    radix_scan<<<8, 256, 0, stream>>>(hist);
    radix_scatter<<<2048, 512, 0, stream>>>(src, dst, hist, shifts[p]);
    u64* tmp = src; src = dst; dst = tmp;
  }

  extract_kernel<<<4096, 256, 0, stream>>>(src, points, sp, sidx);
  patch_kernel<<<M_TOK, 128, 0, stream>>>(sp, W1, b1, W2, b2, Wp1, bp1, Wp2, bp2, comb, cents);
  proj_gemm<<<dim3(1024, 4), 256, 0, stream>>>(comb, Wproj, bproj, tokens);
}

// Round 7
// 653.770 us; speedup vs baseline: 3.0349x; 3.0349x over previous
//
#include <hip/hip_runtime.h>
#include <hip/hip_bf16.h>
#include <stdint.h>

#define B_SZ   8
#define N_PTS  131072
#define L_TOK  8191
#define M_TOK  (B_SZ * L_TOK)   // 65528

typedef unsigned long long u64;
typedef unsigned int u32;
typedef unsigned short u16;
typedef __hip_bfloat16 bf16;
typedef float f32x4 __attribute__((ext_vector_type(4)));
typedef short bf16x8 __attribute__((ext_vector_type(8)));

// ---------- bf16 helpers (RNE, finite inputs) ----------
__device__ __forceinline__ u16 f2bf(float f) {
  u32 u = __float_as_uint(f);
  u32 r = u + 0x7FFFu + ((u >> 16) & 1u);
  return (u16)(r >> 16);
}
__device__ __forceinline__ float bf2f(u16 s) {
  return __uint_as_float(((u32)s) << 16);
}

// ---------- monotonic float<->uint mapping for atomic min/max ----------
__device__ __forceinline__ u32 f2u_mono(float f) {
  u32 u = __float_as_uint(f);
  return (u & 0x80000000u) ? ~u : (u | 0x80000000u);
}
__device__ __forceinline__ float u2f_mono(u32 u) {
  u32 b = (u & 0x80000000u) ? (u ^ 0x80000000u) : ~u;
  return __uint_as_float(b);
}

__global__ void init_mm_kernel(u32* mm) {
  int t = threadIdx.x;
  if (t < 48) mm[t] = ((t % 6) < 3) ? 0xFFFFFFFFu : 0u;
}

// ---------- per-batch per-coord min/max ----------
__global__ __launch_bounds__(256) void minmax_kernel(const float* __restrict__ pts,
                                                     u32* __restrict__ mm) {
  int b = blockIdx.x >> 6;
  int chunk = blockIdx.x & 63;
  int base = b * N_PTS + chunk * 2048;
  float mn0 = 3.4e38f, mn1 = 3.4e38f, mn2 = 3.4e38f;
  float mx0 = -3.4e38f, mx1 = -3.4e38f, mx2 = -3.4e38f;
  for (int i = threadIdx.x; i < 2048; i += 256) {
    const float* p = pts + (size_t)(base + i) * 3;
    float x = p[0], y = p[1], z = p[2];
    mn0 = fminf(mn0, x); mx0 = fmaxf(mx0, x);
    mn1 = fminf(mn1, y); mx1 = fmaxf(mx1, y);
    mn2 = fminf(mn2, z); mx2 = fmaxf(mx2, z);
  }
  __shared__ u32 smn[3], smx[3];
  if (threadIdx.x < 3) { smn[threadIdx.x] = 0xFFFFFFFFu; smx[threadIdx.x] = 0u; }
  __syncthreads();
  atomicMin(&smn[0], f2u_mono(mn0)); atomicMin(&smn[1], f2u_mono(mn1)); atomicMin(&smn[2], f2u_mono(mn2));
  atomicMax(&smx[0], f2u_mono(mx0)); atomicMax(&smx[1], f2u_mono(mx1)); atomicMax(&smx[2], f2u_mono(mx2));
  __syncthreads();
  if (threadIdx.x < 3)       atomicMin(&mm[b * 6 + threadIdx.x], smn[threadIdx.x]);
  else if (threadIdx.x < 6)  atomicMax(&mm[b * 6 + threadIdx.x], smx[threadIdx.x - 3]);
}

// ---------- morton ----------
__device__ __forceinline__ u64 expand_bits(u64 v) {
  v = (v | (v << 32)) & 0x001F00000000FFFFull;
  v = (v | (v << 16)) & 0x001F0000FF0000FFull;
  v = (v | (v << 8))  & 0x100F00F00F00F00Full;
  v = (v | (v << 4))  & 0x10C30C30C30C30C3ull;
  v = (v | (v << 2))  & 0x1249249249249249ull;
  return v;
}

// PROVEN (R6): reciprocal-multiply quantization matches the np grading ref.
// DO NOT TOUCH.
__device__ __forceinline__ long long quant1(float p, float mn, float mx) {
  float scale = fmaxf(mx - mn, 1e-8f);
  float num = p - mn;
  float rcp = 1.0f / scale;
  asm volatile("" : "+v"(rcp));
  float normed = num * rcp;
  asm volatile("" : "+v"(normed));
  float scaled = normed * 1023.0f;
  asm volatile("" : "+v"(scaled));
  long long q = (long long)scaled;
  q = q < 0 ? 0 : q; q = q > 1023 ? 1023 : q;
  return q;
}

__global__ __launch_bounds__(256) void morton_kernel(const float* __restrict__ pts,
                                                     const u32* __restrict__ mm,
                                                     u64* __restrict__ keys) {
  int gid = blockIdx.x * 256 + threadIdx.x;
  int b = gid >> 17;
  int i = gid & (N_PTS - 1);
  const u32* mb = mm + b * 6;
  float mn0 = u2f_mono(mb[0]), mn1 = u2f_mono(mb[1]), mn2 = u2f_mono(mb[2]);
  float mx0 = u2f_mono(mb[3]), mx1 = u2f_mono(mb[4]), mx2 = u2f_mono(mb[5]);
  const float* p = pts + (size_t)gid * 3;
  long long q0 = quant1(p[0], mn0, mx0);
  long long q1 = quant1(p[1], mn1, mx1);
  long long q2 = quant1(p[2], mn2, mx2);
  u64 m = expand_bits((u64)q0) * 4ull + expand_bits((u64)q1) * 2ull + expand_bits((u64)q2);
  keys[gid] = (m << 17) | (u64)i;
}

// ---------- segmented stable LSD radix sort over morton bits ----------
__global__ __launch_bounds__(256) void radix_hist(const u64* __restrict__ keys,
                                                  u32* __restrict__ hist, int shift) {
  int blk = blockIdx.x;
  int b = blk >> 8, c = blk & 255;
  int t = threadIdx.x;
  __shared__ u32 h[256];
  h[t] = 0;
  __syncthreads();
  size_t base = ((size_t)b << 17) + (size_t)c * 512;
  u32 d0 = (u32)((keys[base + t] >> shift) & 255ull);
  u32 d1 = (u32)((keys[base + 256 + t] >> shift) & 255ull);
  atomicAdd(&h[d0], 1u);
  atomicAdd(&h[d1], 1u);
  __syncthreads();
  hist[(blk << 8) + t] = h[t];
}

__global__ __launch_bounds__(256) void radix_scan(u32* __restrict__ hist) {
  int b = blockIdx.x;
  int d = threadIdx.x;
  u32 run = 0;
  for (int c = 0; c < 256; ++c) {
    int idx = ((b * 256 + c) << 8) + d;
    u32 v = hist[idx];
    hist[idx] = run;
    run += v;
  }
  __shared__ u32 s[256];
  s[d] = run;
  __syncthreads();
  for (int off = 1; off < 256; off <<= 1) {
    u32 v = (d >= off) ? s[d - off] : 0u;
    __syncthreads();
    s[d] += v;
    __syncthreads();
  }
  u32 digit_base = s[d] - run;
  for (int c = 0; c < 256; ++c) {
    int idx = ((b * 256 + c) << 8) + d;
    hist[idx] += digit_base;
  }
}

__global__ __launch_bounds__(512) void radix_scatter(const u64* __restrict__ keys_in,
                                                     u64* __restrict__ keys_out,
                                                     const u32* __restrict__ hist, int shift) {
  int blk = blockIdx.x;
  int b = blk >> 8, c = blk & 255;
  int t = threadIdx.x;
  __shared__ u32 cnt[256];
  __shared__ u32 basebuf[256];
  if (t < 256) cnt[t] = hist[(blk << 8) + t];
  __syncthreads();
  size_t base = ((size_t)b << 17) + (size_t)c * 512;
  u64 key = keys_in[base + t];
  u32 d = (u32)((key >> shift) & 255ull);
  int wave = t >> 6, lane = t & 63;
  u32 dst = 0;
  for (int w = 0; w < 8; ++w) {
    if (wave == w) {
      u64 m = ~0ull;
      #pragma unroll
      for (int k = 0; k < 8; ++k) {
        u64 bb = __ballot((d >> k) & 1u);
        m &= ((d >> k) & 1u) ? bb : ~bb;
      }
      u64 lt = (1ull << lane) - 1ull;
      u32 rank = (u32)__popcll(m & lt);
      if (rank == 0)
        basebuf[d] = atomicAdd(&cnt[d], (u32)__popcll(m));
      dst = rank;
    }
    __syncthreads();
    if (wave == w) dst += basebuf[d];
    __syncthreads();
  }
  keys_out[((size_t)b << 17) + dst] = key;
}

// ---------- extract sort_idx + gather sorted points ----------
__global__ __launch_bounds__(256) void extract_kernel(const u64* __restrict__ keys,
                                                      const float* __restrict__ pts,
                                                      float* __restrict__ sp,
                                                      float* __restrict__ sidx) {
  int gid = blockIdx.x * 256 + threadIdx.x;
  u64 key = keys[gid];
  int idx = (int)(key & 0x1FFFFull);
  sidx[gid] = (float)idx;
  int b = gid >> 17;
  const float* src = pts + ((size_t)(b << 17) + idx) * 3;
  float* dst = sp + (size_t)gid * 3;
  dst[0] = src[0]; dst[1] = src[1]; dst[2] = src[2];
}

// ---------- patch MLP via MFMA ----------
// Per block: 64 consecutive patches of one batch (4 waves x 16 patches).
// h = relu(local@W1+b1) computed f32 per lane, split hi/lo bf16 (A-frags).
// W2 split hi/lo bf16 in LDS fragment layout (B-frags).
// feat = 3-pass MFMA (hh + h*lo + lo*h) ~= f32 accuracy; relu+maxpool -> geo.
__global__ __launch_bounds__(256) void patch_kernel(
    const float* __restrict__ sp,
    const float* __restrict__ W1, const float* __restrict__ b1,
    const float* __restrict__ W2, const float* __restrict__ b2,
    bf16* __restrict__ comb, float* __restrict__ cent_out) {
  __shared__ float ptsS[3120];                    // 1040 pts x 3
  __shared__ float cenS[192];                     // 64 x 3
  __shared__ float w1p[256];                      // x,y,z,b1 planes
  __shared__ float b2s[128];
  __shared__ __align__(16) u16 W2frag[16384];     // [pass][kc][nt][lane][8]

  int t = threadIdx.x;
  int bib = blockIdx.x;        // block within batch (0..127)
  int b = blockIdx.y;
  int l0 = bib * 64;
  int pcount = min(64, L_TOK - l0);

  { // stage points (float4 coalesced)
    const float4* src4 = (const float4*)(sp + (size_t)b * (N_PTS * 3) + (size_t)l0 * 48);
    int nvec = min(3120, (N_PTS - l0 * 16) * 3) >> 2;
    float4* dst4 = (float4*)ptsS;
    for (int i = t; i < nvec; i += 256) dst4[i] = src4[i];
  }
  if (t < 64) {
    w1p[t] = W1[t]; w1p[64 + t] = W1[64 + t];
    w1p[128 + t] = W1[128 + t]; w1p[192 + t] = b1[t];
  }
  if (t < 128) b2s[t] = b2[t];
  for (int e = t; e < 8192; e += 256) {   // W2 frag build (hi/lo)
    int k = e >> 7, n = e & 127;
    float v = W2[e];
    u16 hb = f2bf(v);
    u16 lb = f2bf(v - bf2f(hb));
    int kc = k >> 5, q = (k >> 3) & 3, j = k & 7;
    int nt = n >> 4, ln2 = n & 15;
    int base = ((kc * 8 + nt) * 64 + q * 16 + ln2) * 8 + j;
    W2frag[base] = hb;
    W2frag[8192 + base] = lb;
  }
  __syncthreads();

  if (t < 192) {   // centroids (sequential f32 sum, matches previous passing version)
    int pa = t / 3, c = t - pa * 3;
    if (pa < pcount) {
      float s = 0.f;
      for (int i = 0; i < 32; ++i) s += ptsS[(pa * 16 + i) * 3 + c];
      float cv = s * (1.0f / 32.0f);
      cenS[pa * 3 + c] = cv;
      cent_out[(size_t)(b * L_TOK + l0 + pa) * 3 + c] = cv;
    }
  }
  __syncthreads();

  int w = t >> 6, lane = t & 63, ln = lane & 15, quad = lane >> 4;
  const bf16x8* Bf = (const bf16x8*)W2frag;

  for (int ig = 0; ig < 16; ++ig) {
    int ll = w * 16 + ig;
    if (ll >= pcount) break;
    float cx = cenS[ll * 3], cy = cenS[ll * 3 + 1], cz = cenS[ll * 3 + 2];
    float xs[2], ys[2], zs[2];
    #pragma unroll
    for (int mt = 0; mt < 2; ++mt) {
      int row = ll * 16 + mt * 16 + ln;
      xs[mt] = ptsS[row * 3] - cx;
      ys[mt] = ptsS[row * 3 + 1] - cy;
      zs[mt] = ptsS[row * 3 + 2] - cz;
    }
    bf16x8 Ahi[2][2], Alo[2][2];   // [mt][kc]
    #pragma unroll
    for (int kc = 0; kc < 2; ++kc)
      #pragma unroll
      for (int j = 0; j < 8; ++j) {
        int col = kc * 32 + quad * 8 + j;
        float wx = w1p[col], wy = w1p[64 + col], wz = w1p[128 + col], wb = w1p[192 + col];
        #pragma unroll
        for (int mt = 0; mt < 2; ++mt) {
          float h = fmaf(xs[mt], wx, fmaf(ys[mt], wy, fmaf(zs[mt], wz, wb)));
          h = fmaxf(h, 0.f);
          u16 hb = f2bf(h);
          u16 lb = f2bf(h - bf2f(hb));
          Ahi[mt][kc][j] = (short)hb;
          Alo[mt][kc][j] = (short)lb;
        }
      }
    size_t tokoff = (size_t)(b * L_TOK + l0 + ll) * 256;
    #pragma unroll
    for (int half = 0; half < 2; ++half) {
      f32x4 acc[2][4];
      #pragma unroll
      for (int mt = 0; mt < 2; ++mt)
        #pragma unroll
        for (int n4 = 0; n4 < 4; ++n4) acc[mt][n4] = (f32x4){0.f, 0.f, 0.f, 0.f};
      #pragma unroll
      for (int n4 = 0; n4 < 4; ++n4) {
        int nt = half * 4 + n4;
        bf16x8 Bh0 = Bf[(0 * 8 + nt) * 64 + lane];
        bf16x8 Bh1 = Bf[(1 * 8 + nt) * 64 + lane];
        bf16x8 Bl0 = Bf[1024 + (0 * 8 + nt) * 64 + lane];
        bf16x8 Bl1 = Bf[1024 + (1 * 8 + nt) * 64 + lane];
        #pragma unroll
        for (int mt = 0; mt < 2; ++mt) {
          acc[mt][n4] = __builtin_amdgcn_mfma_f32_16x16x32_bf16(Ahi[mt][0], Bh0, acc[mt][n4], 0, 0, 0);
          acc[mt][n4] = __builtin_amdgcn_mfma_f32_16x16x32_bf16(Ahi[mt][1], Bh1, acc[mt][n4], 0, 0, 0);
          acc[mt][n4] = __builtin_amdgcn_mfma_f32_16x16x32_bf16(Alo[mt][0], Bh0, acc[mt][n4], 0, 0, 0);
          acc[mt][n4] = __builtin_amdgcn_mfma_f32_16x16x32_bf16(Alo[mt][1], Bh1, acc[mt][n4], 0, 0, 0);
          acc[mt][n4] = __builtin_amdgcn_mfma_f32_16x16x32_bf16(Ahi[mt][0], Bl0, acc[mt][n4], 0, 0, 0);
          acc[mt][n4] = __builtin_amdgcn_mfma_f32_16x16x32_bf16(Ahi[mt][1], Bl1, acc[mt][n4], 0, 0, 0);
        }
      }
      #pragma unroll
      for (int n4 = 0; n4 < 4; ++n4) {
        int col = (half * 4 + n4) * 16 + ln;
        float bv = b2s[col];
        float m = 0.f;
        #pragma unroll
        for (int mt = 0; mt < 2; ++mt)
          #pragma unroll
          for (int r = 0; r < 4; ++r) m = fmaxf(m, acc[mt][n4][r] + bv);
        m = fmaxf(m, __shfl_xor(m, 16));
        m = fmaxf(m, __shfl_xor(m, 32));
        if (lane < 16) comb[tokoff + col] = __float2bfloat16(m);
      }
    }
  }
}

// ---------- pos MLP via MFMA: 16 patches per wave as M=16 ----------
__global__ __launch_bounds__(256) void pos_kernel(
    const float* __restrict__ cents,
    const float* __restrict__ Wp1, const float* __restrict__ bp1,
    const float* __restrict__ Wp2, const float* __restrict__ bp2,
    bf16* __restrict__ comb) {
  __shared__ float wp[256];
  __shared__ float bp2s[128];
  __shared__ __align__(16) u16 Wfrag[16384];
  int t = threadIdx.x;
  if (t < 64) {
    wp[t] = Wp1[t]; wp[64 + t] = Wp1[64 + t];
    wp[128 + t] = Wp1[128 + t]; wp[192 + t] = bp1[t];
  }
  if (t < 128) bp2s[t] = bp2[t];
  for (int e = t; e < 8192; e += 256) {
    int k = e >> 7, n = e & 127;
    float v = Wp2[e];
    u16 hb = f2bf(v);
    u16 lb = f2bf(v - bf2f(hb));
    int kc = k >> 5, q = (k >> 3) & 3, j = k & 7;
    int nt = n >> 4, ln2 = n & 15;
    int base = ((kc * 8 + nt) * 64 + q * 16 + ln2) * 8 + j;
    Wfrag[base] = hb;
    Wfrag[8192 + base] = lb;
  }
  __syncthreads();
  int w = t >> 6, lane = t & 63, ln = lane & 15, quad = lane >> 4;
  int p0 = blockIdx.x * 64 + w * 16;
  int pm = p0 + ln;
  int pml = min(pm, M_TOK - 1);
  float cx = cents[(size_t)pml * 3], cy = cents[(size_t)pml * 3 + 1], cz = cents[(size_t)pml * 3 + 2];
  bf16x8 Ahi[2], Alo[2];
  #pragma unroll
  for (int kc = 0; kc < 2; ++kc)
    #pragma unroll
    for (int j = 0; j < 8; ++j) {
      int col = kc * 32 + quad * 8 + j;
      float h = fmaf(cx, wp[col], fmaf(cy, wp[64 + col], fmaf(cz, wp[128 + col], wp[192 + col])));
      h = fmaxf(h, 0.f);
      u16 hb = f2bf(h);
      u16 lb = f2bf(h - bf2f(hb));
      Ahi[kc][j] = (short)hb;
      Alo[kc][j] = (short)lb;
    }
  const bf16x8* Bf = (const bf16x8*)Wfrag;
  f32x4 acc[8];
  #pragma unroll
  for (int nt = 0; nt < 8; ++nt) acc[nt] = (f32x4){0.f, 0.f, 0.f, 0.f};
  #pragma unroll
  for (int nt = 0; nt < 8; ++nt) {
    bf16x8 Bh0 = Bf[(0 * 8 + nt) * 64 + lane];
    bf16x8 Bh1 = Bf[(8 + nt) * 64 + lane];
    bf16x8 Bl0 = Bf[1024 + (0 * 8 + nt) * 64 + lane];
    bf16x8 Bl1 = Bf[1024 + (8 + nt) * 64 + lane];
    acc[nt] = __builtin_amdgcn_mfma_f32_16x16x32_bf16(Ahi[0], Bh0, acc[nt], 0, 0, 0);
    acc[nt] = __builtin_amdgcn_mfma_f32_16x16x32_bf16(Ahi[1], Bh1, acc[nt], 0, 0, 0);
    acc[nt] = __builtin_amdgcn_mfma_f32_16x16x32_bf16(Alo[0], Bh0, acc[nt], 0, 0, 0);
    acc[nt] = __builtin_amdgcn_mfma_f32_16x16x32_bf16(Alo[1], Bh1, acc[nt], 0, 0, 0);
    acc[nt] = __builtin_amdgcn_mfma_f32_16x16x32_bf16(Ahi[0], Bl0, acc[nt], 0, 0, 0);
    acc[nt] = __builtin_amdgcn_mfma_f32_16x16x32_bf16(Ahi[1], Bl1, acc[nt], 0, 0, 0);
  }
  #pragma unroll
  for (int nt = 0; nt < 8; ++nt)
    #pragma unroll
    for (int r = 0; r < 4; ++r) {
      int pr = p0 + quad * 4 + r;
      if (pr < M_TOK) {
        float v = acc[nt][r] + bp2s[nt * 16 + ln];
        comb[(size_t)pr * 256 + 128 + nt * 16 + ln] = __float2bfloat16(v);
      }
    }
}

// ---------- token projection GEMM: [M,256] @ [256,256] + bias (f32 VALU) ----------
__global__ __launch_bounds__(256) void proj_gemm(const bf16* __restrict__ A,
                                                 const float* __restrict__ W,
                                                 const float* __restrict__ bias,
                                                 float* __restrict__ C) {
  __shared__ float As[32][65];
  __shared__ float Bs[32][64];
  int t = threadIdx.x;
  int row0 = blockIdx.x * 64, col0 = blockIdx.y * 64;
  int tm = (t >> 4) << 2;
  int tn = (t & 15) << 2;
  float acc[4][4] = {{0.f}};
  for (int kc = 0; kc < 256; kc += 32) {
    #pragma unroll
    for (int e = 0; e < 8; ++e) {
      int idx = t + e * 256;
      int r = idx >> 5, kk = idx & 31;
      int row = row0 + r;
      As[kk][r] = (row < M_TOK) ? __bfloat162float(A[(size_t)row * 256 + kc + kk]) : 0.f;
      int kb = idx >> 6, n = idx & 63;
      Bs[kb][n] = W[(size_t)(kc + kb) * 256 + col0 + n];
    }
    __syncthreads();
    #pragma unroll
    for (int kk = 0; kk < 32; ++kk) {
      float a0 = As[kk][tm], a1 = As[kk][tm + 1], a2 = As[kk][tm + 2], a3 = As[kk][tm + 3];
      float b0 = Bs[kk][tn], b1v = Bs[kk][tn + 1], b2v = Bs[kk][tn + 2], b3v = Bs[kk][tn + 3];
      acc[0][0] = fmaf(a0, b0, acc[0][0]); acc[0][1] = fmaf(a0, b1v, acc[0][1]);
      acc[0][2] = fmaf(a0, b2v, acc[0][2]); acc[0][3] = fmaf(a0, b3v, acc[0][3]);
      acc[1][0] = fmaf(a1, b0, acc[1][0]); acc[1][1] = fmaf(a1, b1v, acc[1][1]);
      acc[1][2] = fmaf(a1, b2v, acc[1][2]); acc[1][3] = fmaf(a1, b3v, acc[1][3]);
      acc[2][0] = fmaf(a2, b0, acc[2][0]); acc[2][1] = fmaf(a2, b1v, acc[2][1]);
      acc[2][2] = fmaf(a2, b2v, acc[2][2]); acc[2][3] = fmaf(a2, b3v, acc[2][3]);
      acc[3][0] = fmaf(a3, b0, acc[3][0]); acc[3][1] = fmaf(a3, b1v, acc[3][1]);
      acc[3][2] = fmaf(a3, b2v, acc[3][2]); acc[3][3] = fmaf(a3, b3v, acc[3][3]);
    }
    __syncthreads();
  }
  float bx = bias[col0 + tn], by = bias[col0 + tn + 1], bz = bias[col0 + tn + 2], bw = bias[col0 + tn + 3];
  #pragma unroll
  for (int i2 = 0; i2 < 4; ++i2) {
    int row = row0 + tm + i2;
    if (row < M_TOK) {
      float4 o;
      o.x = acc[i2][0] + bx; o.y = acc[i2][1] + by;
      o.z = acc[i2][2] + bz; o.w = acc[i2][3] + bw;
      *(float4*)&C[(size_t)row * 256 + col0 + tn] = o;
    }
  }
}

extern "C" void kernel_launch(void* const* d_in, const int* in_sizes, int n_in,
                              void* d_out, int out_size, void* d_ws, size_t ws_size,
                              hipStream_t stream) {
  const float* points = (const float*)d_in[0];
  const float* W1 = (const float*)d_in[1];
  const float* b1 = (const float*)d_in[2];
  const float* W2 = (const float*)d_in[3];
  const float* b2 = (const float*)d_in[4];
  const float* Wp1 = (const float*)d_in[5];
  const float* bp1 = (const float*)d_in[6];
  const float* Wp2 = (const float*)d_in[7];
  const float* bp2 = (const float*)d_in[8];
  const float* Wproj = (const float*)d_in[9];
  const float* bproj = (const float*)d_in[10];

  float* out = (float*)d_out;
  float* tokens = out;                        // [8][8191][256]
  float* cents  = out + 16775168;             // [8][8191][3]
  float* sidx   = out + 16971752;             // [8][131072] as float

  char* ws = (char*)d_ws;
  u32* mm     = (u32*)ws;                                  // 256 B
  u64* keysA  = (u64*)(ws + 256);                          // 8 MB
  float* sp   = (float*)(ws + 256 + 8388608);              // 12 MB
  char* combB = ws + 256 + 8388608 + 12582912;             // 33.5 MB region
  bf16* comb  = (bf16*)combB;
  u64* keysB  = (u64*)combB;                               // aliases comb (dead until extract)
  u32* hist   = (u32*)(combB + 8388608);                   // aliases comb (dead until extract)

  init_mm_kernel<<<1, 64, 0, stream>>>(mm);
  minmax_kernel<<<512, 256, 0, stream>>>(points, mm);
  morton_kernel<<<4096, 256, 0, stream>>>(points, mm, keysA);

  const int shifts[4] = {17, 25, 33, 41};
  u64* src = keysA; u64* dst = keysB;
  for (int p = 0; p < 4; ++p) {
    radix_hist<<<2048, 256, 0, stream>>>(src, hist, shifts[p]);
    radix_scan<<<8, 256, 0, stream>>>(hist);
    radix_scatter<<<2048, 512, 0, stream>>>(src, dst, hist, shifts[p]);
    u64* tmp = src; src = dst; dst = tmp;
  }

  extract_kernel<<<4096, 256, 0, stream>>>(src, points, sp, sidx);
  patch_kernel<<<dim3(128, 8), 256, 0, stream>>>(sp, W1, b1, W2, b2, comb, cents);
  pos_kernel<<<1024, 256, 0, stream>>>(cents, Wp1, bp1, Wp2, bp2, comb);
  proj_gemm<<<dim3(1024, 4), 256, 0, stream>>>(comb, Wproj, bproj, tokens);
}